// Round 1
// baseline (90.044 us; speedup 1.0000x reference)
//
#include <hip/hip_runtime.h>

// ChebFCN2D: out[n,o] = b[o] + W[o,0] + sum_{i=1..31} T_i(x) * (sum_{j=1..31} W[o,1+(i-1)*31+(j-1)] * T_j(y))
// N = 262144 points, W: [3,962] f32, out: [N,3] f32.
// VALU-bound (~1.57 GFLOP fp32, 157 TF roofline ~10us). W reads are wave-uniform -> s_load via K$.

#define LSZ 32      // number of Chebyshev polys T_0..T_31
#define NP 31       // active polys per axis (1..31)
#define FEAT 962

__global__ __launch_bounds__(256) void cheb_fcn2d_kernel(
    const float* __restrict__ x,   // [N,2]
    const float* __restrict__ W,   // [3,962]
    const float* __restrict__ b,   // [3]
    float* __restrict__ out,       // [N,3]
    int N)
{
    int n = blockIdx.x * blockDim.x + threadIdx.x;
    if (n >= N) return;

    float2 xy = *reinterpret_cast<const float2*>(x + 2 * (size_t)n);
    float x0 = xy.x, y0 = xy.y;

    // Chebyshev features of y, fully unrolled -> compile-time register indices.
    float Y[LSZ];
    Y[0] = 1.0f;
    Y[1] = y0;
    float ty2 = 2.0f * y0;
#pragma unroll
    for (int k = 2; k < LSZ; ++k) {
        Y[k] = ty2 * Y[k - 1] - Y[k - 2];
    }

    float acc0 = b[0] + W[0 * FEAT];
    float acc1 = b[1] + W[1 * FEAT];
    float acc2 = b[2] + W[2 * FEAT];

    // Rolling Chebyshev recurrence for x (avoids runtime-indexed reg array).
    float tx2 = 2.0f * x0;
    float xpp = 1.0f;   // T_0(x)
    float xp  = x0;     // T_1(x)

    for (int i = 1; i < LSZ; ++i) {
        const float* w0 = W + 0 * FEAT + 1 + (i - 1) * NP;
        const float* w1 = W + 1 * FEAT + 1 + (i - 1) * NP;
        const float* w2 = W + 2 * FEAT + 1 + (i - 1) * NP;

        // Two partial sums per output to shorten FMA dep chains.
        float s0a = 0.f, s0b = 0.f;
        float s1a = 0.f, s1b = 0.f;
        float s2a = 0.f, s2b = 0.f;
#pragma unroll
        for (int j = 1; j < LSZ; j += 2) {
            s0a += w0[j - 1] * Y[j];
            s1a += w1[j - 1] * Y[j];
            s2a += w2[j - 1] * Y[j];
            if (j + 1 < LSZ) {
                s0b += w0[j] * Y[j + 1];
                s1b += w1[j] * Y[j + 1];
                s2b += w2[j] * Y[j + 1];
            }
        }

        float xi = xp;
        acc0 += xi * (s0a + s0b);
        acc1 += xi * (s1a + s1b);
        acc2 += xi * (s2a + s2b);

        float xn = tx2 * xp - xpp;
        xpp = xp;
        xp = xn;
    }

    out[3 * (size_t)n + 0] = acc0;
    out[3 * (size_t)n + 1] = acc1;
    out[3 * (size_t)n + 2] = acc2;
}

extern "C" void kernel_launch(void* const* d_in, const int* in_sizes, int n_in,
                              void* d_out, int out_size, void* d_ws, size_t ws_size,
                              hipStream_t stream) {
    const float* x = (const float*)d_in[0];   // [N,2]
    const float* W = (const float*)d_in[1];   // [3,962]
    const float* b = (const float*)d_in[2];   // [3]
    float* out = (float*)d_out;               // [N,3]

    int N = in_sizes[0] / 2;
    int block = 256;
    int grid = (N + block - 1) / block;
    cheb_fcn2d_kernel<<<grid, block, 0, stream>>>(x, W, b, out, N);
}